// Round 1
// baseline (429.627 us; speedup 1.0000x reference)
//
#include <hip/hip_runtime.h>
#include <cstdint>
#include <cmath>

// ---------------------------------------------------------------------------
// WignerD: out[b] = block-diag over IRREPS_L=[0]*32+[1]*16+[2]*8+[3]*8+[4]*4
// of Dl(b) = Zrot(l,alpha) @ A[l] @ Zrot(l,beta) @ AINV[l] @ Zrot(l,gamma).
// DIM = 212, B = 2048, out = (B,212,212) fp32 = 368 MB (97.6% zeros).
//
// A[l] (Wigner of the fixed rotation _RX) is recomputed on-device every launch
// by a tiny setup kernel: least-squares fit of real-SH values at 48
// deterministic points (the fit is exact/point-independent since SH rotation
// is an exact linear map). A is orthogonal => AINV = A^T.
// ---------------------------------------------------------------------------

#define WDIM 212
#define NBLK 165    // sum over l of (2l+1)^2
#define NWRITE 1092 // sum over irreps of (2l+1)^2

__device__ __constant__ int c_moff[5] = {0, 1, 10, 35, 84};

struct TabM { unsigned char l[NBLK], i[NBLK], j[NBLK]; };
constexpr TabM make_tabM() {
  TabM t{};
  int idx = 0;
  for (int l = 0; l < 5; l++) {
    int n = 2 * l + 1;
    for (int i = 0; i < n; i++)
      for (int j = 0; j < n; j++) {
        t.l[idx] = (unsigned char)l;
        t.i[idx] = (unsigned char)i;
        t.j[idx] = (unsigned char)j;
        idx++;
      }
  }
  return t;
}
__device__ __constant__ TabM c_tabM = make_tabM();

struct TabW { unsigned short off[NWRITE]; unsigned char l[NWRITE], i[NWRITE], j[NWRITE]; };
constexpr TabW make_tabW() {
  TabW t{};
  const int cnt[5] = {32, 16, 8, 8, 4};
  const int start[5] = {0, 32, 80, 120, 176};
  int idx = 0;
  for (int l = 0; l < 5; l++) {
    int n = 2 * l + 1;
    for (int c = 0; c < cnt[l]; c++) {
      int off = start[l] + c * n;
      for (int i = 0; i < n; i++)
        for (int j = 0; j < n; j++) {
          t.off[idx] = (unsigned short)off;
          t.l[idx] = (unsigned char)l;
          t.i[idx] = (unsigned char)i;
          t.j[idx] = (unsigned char)j;
          idx++;
        }
    }
  }
  return t;
}
__device__ __constant__ TabW c_tabW = make_tabW();

// A[165] then AINV[165], written by setup kernel each launch.
__device__ float g_ws[330];

// splitmix64 -> double in [-1,1)
__device__ inline double rnd_double(uint64_t x) {
  x += 0x9E3779B97F4A7C15ull;
  x = (x ^ (x >> 30)) * 0xBF58476D1CE4E5B9ull;
  x = (x ^ (x >> 27)) * 0x94D049BB133111EBull;
  x ^= x >> 31;
  return (double)(x >> 11) * (1.0 / 4503599627370496.0) - 1.0;
}

// Real spherical harmonics, same convention as the reference (CS phase inside P).
__device__ void eval_real_sh(int l, const double p[3], double* outv) {
  const double x = p[0], y = p[1], z = p[2];
  const double phi = atan2(y, x);
  double P[5];
  for (int m = 0; m <= l; m++) {
    double pmm = 1.0;
    if (m > 0) {
      double somx2 = sqrt(fmax(1.0 - z * z, 0.0));
      double fct = 1.0;
      for (int k = 0; k < m; k++) { pmm = -pmm * fct * somx2; fct += 2.0; }
    }
    if (l == m) { P[m] = pmm; continue; }
    double pmmp1 = z * (2 * m + 1) * pmm;
    if (l == m + 1) { P[m] = pmmp1; continue; }
    for (int ll = m + 2; ll <= l; ll++) {
      double pll = ((2 * ll - 1) * z * pmmp1 - (ll + m - 1) * pmm) / (double)(ll - m);
      pmm = pmmp1;
      pmmp1 = pll;
    }
    P[m] = pmmp1;
  }
  const double fact[9] = {1, 1, 2, 6, 24, 120, 720, 5040, 40320};
  const double four_pi = 4.0 * 3.14159265358979323846;
  for (int m = -l; m <= l; m++) {
    int am = m < 0 ? -m : m;
    double N = sqrt((2 * l + 1) / four_pi * fact[l - am] / fact[l + am]);
    double v;
    if (m == 0) v = N * P[0];
    else if (m > 0) v = sqrt(2.0) * N * P[am] * cos(m * phi);
    else v = sqrt(2.0) * N * P[am] * sin(am * phi);
    outv[m + l] = v;
  }
}

// One wave per l (5 waves). Least-squares A from 48 sample points, then
// AINV = A^T (A is orthogonal). Doubles throughout; store float to g_ws.
__global__ __launch_bounds__(320) void wigner_setup() {
  const int l = threadIdx.x >> 6;
  const int lane = threadIdx.x & 63;
  const int n = 2 * l + 1;

  __shared__ double Y[5][48][9];
  __shared__ double Yr[5][48][9];
  __shared__ double G[5][9][18]; // [G | C] augmented
  __shared__ double F[5][9];

  if (lane < 48) {
    uint64_t base = ((uint64_t)l * 1024u + (uint64_t)lane) * 4u + 1u;
    double p[3];
    double nrm2 = 0.0;
    for (int c = 0; c < 3; c++) { p[c] = rnd_double(base + (uint64_t)c); nrm2 += p[c] * p[c]; }
    if (nrm2 < 1e-12) { p[0] = 1.0; p[1] = 0.5; p[2] = 0.25; nrm2 = 1.3125; }
    double invn = 1.0 / sqrt(nrm2);
    p[0] *= invn; p[1] *= invn; p[2] *= invn;
    double q[3] = { p[0], p[2], -p[1] }; // _RX applied: (x,y,z) -> (x,z,-y)
    eval_real_sh(l, p, &Y[l][lane][0]);
    eval_real_sh(l, q, &Yr[l][lane][0]);
  }
  __syncthreads();

  // Normal equations: G = Y^T Y (pad to I), C = Y^T Yr (pad 0)
  for (int e = lane; e < 162; e += 64) {
    int r = e / 18, c = e % 18;
    double v;
    if (c < 9) {
      if (r < n && c < n) {
        v = 0.0;
        for (int s = 0; s < 48; s++) v += Y[l][s][r] * Y[l][s][c];
      } else v = (r == c) ? 1.0 : 0.0;
    } else {
      int cc = c - 9;
      if (r < n && cc < n) {
        v = 0.0;
        for (int s = 0; s < 48; s++) v += Y[l][s][r] * Yr[l][s][cc];
      } else v = 0.0;
    }
    G[l][r][c] = v;
  }
  __syncthreads();

  // Gauss-Jordan (G is SPD + identity padding: no pivoting needed)
  for (int k = 0; k < 9; k++) {
    double ipiv = 1.0 / G[l][k][k];
    if (lane < 18) G[l][k][lane] *= ipiv;
    __syncthreads();
    if (lane < 9) F[l][lane] = G[l][lane][k];
    __syncthreads();
    for (int e = lane; e < 162; e += 64) {
      int r = e / 18, c = e % 18;
      if (r != k) G[l][r][c] -= F[l][r] * G[l][k][c];
    }
    __syncthreads();
  }

  // X = right half solves Yx@X ~= Yrx ; A = X^T ; AINV = A^T = X
  for (int e = lane; e < n * n; e += 64) {
    int i = e / n, j = e % n;
    ws_store:;
    g_ws[c_moff[l] + e]       = (float)G[l][j][9 + i]; // A[i][j]
    g_ws[165 + c_moff[l] + e] = (float)G[l][i][9 + j]; // AINV[i][j]
  }
}

// One block per batch element.
__global__ __launch_bounds__(256) void wigner_main(const float* __restrict__ alpha,
                                                   const float* __restrict__ beta,
                                                   const float* __restrict__ gamma,
                                                   float* __restrict__ out) {
  const int b = blockIdx.x;
  const int tid = threadIdx.x;
  const float a = alpha[b];
  const float be = beta[b];
  const float g = gamma[b];

  __shared__ float sA[330]; // A then AINV
  __shared__ float sT[NBLK];
  __shared__ float sM[NBLK];

  for (int e = tid; e < 330; e += 256) sA[e] = g_ws[e];
  __syncthreads();

  // T = Zbeta @ AINV  (Z row i: cos(m_i b) at i, -sin(m_i b) at n-1-i)
  for (int e = tid; e < NBLK; e += 256) {
    int l = c_tabM.l[e], i = c_tabM.i[e], j = c_tabM.j[e];
    int n = 2 * l + 1, moff = c_moff[l];
    int i2 = n - 1 - i;
    float mi = (float)(i - l);
    float sb, cb;
    __sincosf(mi * be, &sb, &cb);
    sT[e] = cb * sA[165 + moff + i * n + j] - sb * sA[165 + moff + i2 * n + j];
  }
  __syncthreads();

  // M = A @ T
  for (int e = tid; e < NBLK; e += 256) {
    int l = c_tabM.l[e], i = c_tabM.i[e], j = c_tabM.j[e];
    int n = 2 * l + 1, moff = c_moff[l];
    float acc = 0.f;
    for (int k = 0; k < n; k++) acc += sA[moff + i * n + k] * sT[moff + k * n + j];
    sM[e] = acc;
  }
  __syncthreads();

  // D[i,j] = cos(mi*a)*(M[i,j]cg + M[i,j']sg) - sin(mi*a)*(M[i',j]cg + M[i',j']sg)
  const size_t obase = (size_t)b * (WDIM * WDIM);
  for (int t = tid; t < NWRITE; t += 256) {
    int l = c_tabW.l[t], i = c_tabW.i[t], j = c_tabW.j[t];
    int off = c_tabW.off[t];
    int n = 2 * l + 1, moff = c_moff[l];
    int i2 = n - 1 - i, j2 = n - 1 - j;
    float mi = (float)(i - l), mj = (float)(j - l);
    float sa, ca, sg, cg;
    __sincosf(mi * a, &sa, &ca);
    __sincosf(mj * g, &sg, &cg);
    float r0 = sM[moff + i * n + j] * cg + sM[moff + i * n + j2] * sg;
    float r1 = sM[moff + i2 * n + j] * cg + sM[moff + i2 * n + j2] * sg;
    out[obase + (size_t)(off + i) * WDIM + (off + j)] = ca * r0 - sa * r1;
  }
}

extern "C" void kernel_launch(void* const* d_in, const int* in_sizes, int n_in,
                              void* d_out, int out_size, void* d_ws, size_t ws_size,
                              hipStream_t stream) {
  const float* alpha = (const float*)d_in[0];
  const float* beta  = (const float*)d_in[1];
  const float* gamma = (const float*)d_in[2];
  float* out = (float*)d_out;
  const int B = in_sizes[0];

  // Recompute A/AINV constants (identical work every call; graph-safe).
  wigner_setup<<<1, 320, 0, stream>>>();
  // Zero the 368 MB output (97.6% of it stays zero).
  hipMemsetAsync(d_out, 0, (size_t)out_size * sizeof(float), stream);
  // Fill the block-diagonal entries.
  wigner_main<<<B, 256, 0, stream>>>(alpha, beta, gamma, out);
}